// Round 1
// baseline (287.943 us; speedup 1.0000x reference)
//
#include <hip/hip_runtime.h>

#define NBQ 12544
#define DM  256
#define MM  2048

typedef __attribute__((ext_vector_type(8)))  __bf16 bf16x8;
typedef __attribute__((ext_vector_type(4)))  float  floatx4;

__device__ __forceinline__ ushort f2bf(float x) {
    unsigned u = __float_as_uint(x);
    u += 0x7fffu + ((u >> 16) & 1u);   // RNE
    return (ushort)(u >> 16);
}
__device__ __forceinline__ float bf2f(ushort h) {
    return __uint_as_float(((unsigned)h) << 16);
}

// async global->LDS, 16B per lane; dest = wave-uniform base + lane*16
__device__ __forceinline__ void glds16(const ushort* g, ushort* l) {
    __builtin_amdgcn_global_load_lds(
        (const __attribute__((address_space(1))) unsigned int*)g,
        (__attribute__((address_space(3))) unsigned int*)l, 16, 0, 0);
}

// ---------- projections, weight-pairs folded (r11/r12/r13-proven) ----------
__global__ __launch_bounds__(256) void gemm_proj_all(
    const float* __restrict__ x,      const float* __restrict__ ch_mem,
    const float* __restrict__ ch_wq,  const float* __restrict__ ch_wk,
    const float* __restrict__ ch_wv,  const float* __restrict__ sp_mem,
    const float* __restrict__ sp_wq,  const float* __restrict__ sp_wk,
    const float* __restrict__ sp_wv,
    ushort* __restrict__ Qb,  ushort* __restrict__ QFb,
    ushort* __restrict__ Kb,  ushort* __restrict__ KFb,
    ushort* __restrict__ Vtb, ushort* __restrict__ VFtb)
{
    __shared__ ushort As[64][72];
    __shared__ ushort W1s[64][72];
    __shared__ ushort W2s[64][72];

    int bid = blockIdx.x;
    const float* A; const float* W1; const float* W2;
    ushort* C1; ushort* C2; int nrows, trans2;
    if (bid < 784) {
        A = x; W1 = ch_wq; W2 = sp_wq; C1 = Qb; C2 = QFb; nrows = NBQ; trans2 = 0;
    } else if (bid < 912) {
        A = ch_mem; W1 = ch_wk; W2 = ch_wv; C1 = Kb; C2 = Vtb;
        nrows = MM; trans2 = 1; bid -= 784;
    } else {
        A = sp_mem; W1 = sp_wk; W2 = sp_wv; C1 = KFb; C2 = VFtb;
        nrows = MM; trans2 = 1; bid -= 912;
    }
    const int r0 = (bid >> 2) * 64;
    const int c0 = (bid & 3) * 64;

    const int tid  = threadIdx.x;
    const int wv   = tid >> 6;
    const int lane = tid & 63;
    const int quad = lane >> 4;
    const int l16  = lane & 15;
    const int rw = (wv & 1) * 32;
    const int cw = (wv >> 1) * 32;

    floatx4 acc1[2][2], acc2[2][2];
    #pragma unroll
    for (int i = 0; i < 2; ++i)
        #pragma unroll
        for (int j = 0; j < 2; ++j) {
            acc1[i][j] = (floatx4){0.f, 0.f, 0.f, 0.f};
            acc2[i][j] = (floatx4){0.f, 0.f, 0.f, 0.f};
        }

    for (int d0 = 0; d0 < 256; d0 += 64) {
        __syncthreads();
        #pragma unroll
        for (int it = 0; it < 4; ++it) {
            int idx = tid + it * 256;
            int r = idx >> 4, c4 = (idx & 15) * 4;
            float4 a4 = *(const float4*)(A  + (size_t)(r0 + r) * 256 + d0 + c4);
            float4 w14 = *(const float4*)(W1 + (size_t)(c0 + r) * 256 + d0 + c4);
            float4 w24 = *(const float4*)(W2 + (size_t)(c0 + r) * 256 + d0 + c4);
            ushort4 ab, w1b, w2b;
            ab.x = f2bf(a4.x);  ab.y = f2bf(a4.y);  ab.z = f2bf(a4.z);  ab.w = f2bf(a4.w);
            w1b.x = f2bf(w14.x); w1b.y = f2bf(w14.y); w1b.z = f2bf(w14.z); w1b.w = f2bf(w14.w);
            w2b.x = f2bf(w24.x); w2b.y = f2bf(w24.y); w2b.z = f2bf(w24.z); w2b.w = f2bf(w24.w);
            *(ushort4*)&As[r][c4]  = ab;
            *(ushort4*)&W1s[r][c4] = w1b;
            *(ushort4*)&W2s[r][c4] = w2b;
        }
        __syncthreads();
        #pragma unroll
        for (int kk = 0; kk < 64; kk += 32) {
            bf16x8 aA0 = *(const bf16x8*)&As[rw + l16][kk + quad * 8];
            bf16x8 aA1 = *(const bf16x8*)&As[rw + 16 + l16][kk + quad * 8];
            bf16x8 b10 = *(const bf16x8*)&W1s[cw + l16][kk + quad * 8];
            bf16x8 b11 = *(const bf16x8*)&W1s[cw + 16 + l16][kk + quad * 8];
            bf16x8 b20 = *(const bf16x8*)&W2s[cw + l16][kk + quad * 8];
            bf16x8 b21 = *(const bf16x8*)&W2s[cw + 16 + l16][kk + quad * 8];
            acc1[0][0] = __builtin_amdgcn_mfma_f32_16x16x32_bf16(aA0, b10, acc1[0][0], 0, 0, 0);
            acc1[0][1] = __builtin_amdgcn_mfma_f32_16x16x32_bf16(aA0, b11, acc1[0][1], 0, 0, 0);
            acc1[1][0] = __builtin_amdgcn_mfma_f32_16x16x32_bf16(aA1, b10, acc1[1][0], 0, 0, 0);
            acc1[1][1] = __builtin_amdgcn_mfma_f32_16x16x32_bf16(aA1, b11, acc1[1][1], 0, 0, 0);
            acc2[0][0] = __builtin_amdgcn_mfma_f32_16x16x32_bf16(aA0, b20, acc2[0][0], 0, 0, 0);
            acc2[0][1] = __builtin_amdgcn_mfma_f32_16x16x32_bf16(aA0, b21, acc2[0][1], 0, 0, 0);
            acc2[1][0] = __builtin_amdgcn_mfma_f32_16x16x32_bf16(aA1, b20, acc2[1][0], 0, 0, 0);
            acc2[1][1] = __builtin_amdgcn_mfma_f32_16x16x32_bf16(aA1, b21, acc2[1][1], 0, 0, 0);
        }
    }

    #pragma unroll
    for (int ag = 0; ag < 2; ++ag)
        #pragma unroll
        for (int cg = 0; cg < 2; ++cg)
            #pragma unroll
            for (int i = 0; i < 4; ++i)
                C1[(size_t)(r0 + rw + ag * 16 + quad * 4 + i) * 256
                   + c0 + cw + cg * 16 + l16] = f2bf(acc1[ag][cg][i]);

    if (!trans2) {
        #pragma unroll
        for (int ag = 0; ag < 2; ++ag)
            #pragma unroll
            for (int cg = 0; cg < 2; ++cg)
                #pragma unroll
                for (int i = 0; i < 4; ++i)
                    C2[(size_t)(r0 + rw + ag * 16 + quad * 4 + i) * 256
                       + c0 + cw + cg * 16 + l16] = f2bf(acc2[ag][cg][i]);
    } else {
        __syncthreads();
        #pragma unroll
        for (int ag = 0; ag < 2; ++ag)
            #pragma unroll
            for (int cg = 0; cg < 2; ++cg)
                #pragma unroll
                for (int i = 0; i < 4; ++i)
                    W2s[cw + cg * 16 + l16][rw + ag * 16 + quad * 4 + i] = f2bf(acc2[ag][cg][i]);
        __syncthreads();
        const int col = tid >> 2;
        const int seg = (tid & 3) * 16;
        #pragma unroll
        for (int j = 0; j < 2; ++j)
            *(uint4*)(C2 + (size_t)(c0 + col) * nrows + r0 + seg + j * 8) =
                *(const uint4*)&W2s[col][seg + j * 8];
    }
}

// ---------------- KF row stats only (Q stats inline in fused) ----------------
__global__ __launch_bounds__(256) void row_stats_kf(
    const ushort* __restrict__ KFb, float* __restrict__ km, float* __restrict__ kv)
{
    const int row  = blockIdx.x * 4 + (threadIdx.x >> 6);
    const int lane = threadIdx.x & 63;
    ushort4 u = *(const ushort4*)(KFb + (size_t)row * 256 + lane * 4);
    float a = bf2f(u.x), b = bf2f(u.y), c = bf2f(u.z), d = bf2f(u.w);
    float s  = a + b + c + d;
    float ss = a * a + b * b + c * c + d * d;
    #pragma unroll
    for (int off = 32; off > 0; off >>= 1) {
        s  += __shfl_down(s, off);
        ss += __shfl_down(ss, off);
    }
    if (lane == 0) {
        float m = s * (1.f / 256.f);
        km[row] = m;
        kv[row] = (ss - 256.f * m * m) * (1.f / 255.f);
    }
}

// ---------------- fused dual attention, MEM-split + async glds staging ------------
// NHALF=2: 784 blocks, each does 1024 of MEM, writes unnormalized per-branch partials
//          (combine_halves finishes). NHALF=1: 392 blocks, direct out (ws fallback).
// Staging via global_load_lds w=16 into LINEAR LDS; the pr row permutation and an XOR
// chunk swizzle are applied on the per-lane GLOBAL source address (m201/m173 pattern),
// so MFMA operands are bit-identical to the r13 kernel but ds_reads are conflict-even
// and staging has no VGPR round-trip. K+V co-staged at tile top (r7/r15: phase-split
// staging regresses 2x). LDS 64 KB -> 2 blocks/CU.
template<int NHALF>
__global__ __launch_bounds__(256, 2) void fused_attn_st(
    const ushort* __restrict__ Qb,  const ushort* __restrict__ QFb,
    const ushort* __restrict__ Kb,  const ushort* __restrict__ KFb,
    const ushort* __restrict__ Vtb, const ushort* __restrict__ VFtb,
    const float* __restrict__ km_, const float* __restrict__ kv_,
    float* __restrict__ out, float* __restrict__ part, float* __restrict__ denp)
{
    __shared__ ushort SMu[32768];          // 65536 B: K[0,8K) KF[8K,16K) Vt[16K,24K) VFt[24K,32K) (ushort idx)
    float* combuf = (float*)SMu;           // NHALF==1 epilogue alias (32 KB over K/KF)

    const int tid  = threadIdx.x;
    const int wv   = tid >> 6;
    const int lane = tid & 63;
    const int quad = lane >> 4;
    const int l16  = lane & 15;
    const int qsel = wv & 1;
    const int br   = wv >> 1;          // 0 = channel, 1 = spatial

    const int bid   = blockIdx.x;
    const int half  = (NHALF == 2) ? (bid & 1) : 0;
    const int qc    = (NHALF == 2) ? (bid >> 1) : bid;
    const int q0    = qc * 32;
    const int kbase = half * (MM / NHALF);
    const int NT    = (MM / NHALF) / 32;

    const ushort* qsrc = br ? QFb : Qb;
    bf16x8 aQ[8];
    {
        const ushort* qp = qsrc + (size_t)(q0 + qsel * 16 + l16) * DM + quad * 8;
        #pragma unroll
        for (int s = 0; s < 8; ++s) aQ[s] = *(const bf16x8*)(qp + s * 32);
    }

    float qmv = 0.f, qvv = 0.f;
    if (br) {
        float sum = 0.f, ss = 0.f;
        #pragma unroll
        for (int s = 0; s < 8; ++s)
            #pragma unroll
            for (int j = 0; j < 8; ++j) {
                float v = (float)aQ[s][j];
                sum += v; ss += v * v;
            }
        sum += __shfl_xor(sum, 16, 64); sum += __shfl_xor(sum, 32, 64);
        ss  += __shfl_xor(ss, 16, 64);  ss  += __shfl_xor(ss, 32, 64);
        qmv = sum * (1.f / 256.f);
        qvv = (ss - 256.f * qmv * qmv) * (1.f / 255.f);
    }

    // per-lane staging source offsets (element units).
    // K-type LDS row R holds mem row prinv(R), LDS chunk sc holds src chunk sc^(R&7).
    // V-type LDS row R=d, LDS chunk qc holds src chunk qc^(R&3).
    int offK[4], offV[4];
    #pragma unroll
    for (int p = 0; p < 4; ++p) {
        int j  = wv * 4 + p;
        int Rk = 2 * j + (lane >> 5);
        int rk = (Rk & 3) + ((Rk >> 4) & 1) * 4 + ((Rk >> 2) & 3) * 8;   // prinv
        int ck = (lane & 31) ^ (Rk & 7);
        offK[p] = rk * DM + ck * 8;
        int Rv = 16 * j + (lane >> 2);
        int cv = (lane & 3) ^ (Rv & 3);
        offV[p] = Rv * MM + cv * 8;
    }

    const ushort* kp  = Kb   + (size_t)kbase * DM;
    const ushort* kfp = KFb  + (size_t)kbase * DM;
    const ushort* vp  = Vtb  + kbase;
    const ushort* vfp = VFtb + kbase;

    floatx4 acc[16];
    #pragma unroll
    for (int t = 0; t < 16; ++t) acc[t] = (floatx4){0.f, 0.f, 0.f, 0.f};
    float den = 0.f;

    const int ksw  = l16 & 7;
    const int vswo = (quad ^ (l16 & 3)) * 8;

    for (int ti = 0; ti < NT; ++ti) {
        __syncthreads();
        #pragma unroll
        for (int p = 0; p < 4; ++p) {
            int db = (wv * 4 + p) * 512;           // ushort idx; 1 KB per wave-issue
            glds16(kp  + offK[p], SMu + db);
            glds16(kfp + offK[p], SMu + 8192 + db);
            glds16(vp  + offV[p], SMu + 16384 + db);
            glds16(vfp + offV[p], SMu + 24576 + db);
        }
        kp += 32 * DM; kfp += 32 * DM; vp += 32; vfp += 32;
        __syncthreads();                            // drains vmcnt -> LDS visible

        const ushort* Ks = SMu + (br ? 8192 : 0);
        floatx4 S0 = (floatx4){0.f, 0.f, 0.f, 0.f};
        floatx4 S1 = (floatx4){0.f, 0.f, 0.f, 0.f};
        #pragma unroll
        for (int s = 0; s < 8; ++s) {
            int off = (((s * 4 + quad) ^ ksw)) * 8;
            bf16x8 aK0 = *(const bf16x8*)(Ks + l16 * DM + off);
            bf16x8 aK1 = *(const bf16x8*)(Ks + 4096 + l16 * DM + off);
            S0 = __builtin_amdgcn_mfma_f32_16x16x32_bf16(aK0, aQ[s], S0, 0, 0, 0);
            S1 = __builtin_amdgcn_mfma_f32_16x16x32_bf16(aK1, aQ[s], S1, 0, 0, 0);
        }

        const int kk = kbase + ti * 32;
        float pb[8];
        if (!br) {
            #pragma unroll
            for (int r = 0; r < 4; ++r) {
                pb[r]     = __expf(S0[r] * 0.0625f);
                pb[4 + r] = __expf(S1[r] * 0.0625f);
            }
        } else {
            floatx4 km0 = *(const floatx4*)(km_ + kk + 8 * quad);
            floatx4 km1 = *(const floatx4*)(km_ + kk + 8 * quad + 4);
            floatx4 kv0 = *(const floatx4*)(kv_ + kk + 8 * quad);
            floatx4 kv1 = *(const floatx4*)(kv_ + kk + 8 * quad + 4);
            #pragma unroll
            for (int r = 0; r < 4; ++r) {
                {
                    float mp  = qmv * km0[r];
                    float cov = (S0[r] - 256.f * mp) * (1.f / 255.f);
                    float num = (2.f * mp + 0.01f) * (2.f * cov + 0.03f);
                    float dn  = (qmv * qmv + km0[r] * km0[r] + 0.01f) * (qvv + kv0[r] + 0.03f);
                    pb[r] = __expf(num / (dn + 1e-8f));
                }
                {
                    float mp  = qmv * km1[r];
                    float cov = (S1[r] - 256.f * mp) * (1.f / 255.f);
                    float num = (2.f * mp + 0.01f) * (2.f * cov + 0.03f);
                    float dn  = (qmv * qmv + km1[r] * km1[r] + 0.01f) * (qvv + kv1[r] + 0.03f);
                    pb[4 + r] = __expf(num / (dn + 1e-8f));
                }
            }
        }
        union { ushort u[8]; bf16x8 v; } ap;
        #pragma unroll
        for (int j = 0; j < 8; ++j) {
            den += pb[j];
            ap.u[j] = f2bf(pb[j]);
        }

        const ushort* Vs = SMu + (br ? 24576 : 16384);
        #pragma unroll
        for (int t = 0; t < 16; ++t) {
            bf16x8 bV = *(const bf16x8*)(Vs + (t * 16 + l16) * 32 + vswo);
            acc[t] = __builtin_amdgcn_mfma_f32_16x16x32_bf16(ap.v, bV, acc[t], 0, 0, 0);
        }
    }

    den += __shfl_xor(den, 16, 64);
    den += __shfl_xor(den, 32, 64);

    if (NHALF == 1) {
        float rdn[4];
        #pragma unroll
        for (int r = 0; r < 4; ++r)
            rdn[r] = 1.f / __shfl(den, quad * 4 + r, 64);

        __syncthreads();
        if (br) {
            #pragma unroll
            for (int t = 0; t < 16; ++t)
                #pragma unroll
                for (int r = 0; r < 4; ++r)
                    combuf[(qsel * 16 + quad * 4 + r) * 256 + t * 16 + l16] = acc[t][r] * rdn[r];
        }
        __syncthreads();
        if (!br) {
            #pragma unroll
            for (int t = 0; t < 16; ++t)
                #pragma unroll
                for (int r = 0; r < 4; ++r) {
                    int ql = qsel * 16 + quad * 4 + r;
                    out[(size_t)(q0 + ql) * DM + t * 16 + l16] =
                        acc[t][r] * rdn[r] + combuf[ql * 256 + t * 16 + l16];
                }
        }
    } else {
        float* Np = part + (size_t)(half * 2 + br) * ((size_t)NBQ * DM);
        #pragma unroll
        for (int t = 0; t < 16; ++t)
            #pragma unroll
            for (int r = 0; r < 4; ++r)
                Np[(size_t)(q0 + qsel * 16 + quad * 4 + r) * DM + t * 16 + l16] = acc[t][r];
        if (lane < 16)
            denp[(size_t)(half * 2 + br) * NBQ + q0 + qsel * 16 + lane] = den;
    }
}

// ---------------- combine the two MEM-halves (per-branch normalize, sum) ----------
__global__ __launch_bounds__(256) void combine_halves(
    const float* __restrict__ part, const float* __restrict__ denp,
    float* __restrict__ out)
{
    const size_t stride = (size_t)NBQ * 64;         // float4 units per section
    const float4* p4 = (const float4*)part;
    float4* o4 = (float4*)out;
    #pragma unroll
    for (int u = 0; u < 2; ++u) {
        size_t i = (size_t)blockIdx.x * 512 + (size_t)u * 256 + threadIdx.x;
        int q = (int)(i >> 6);
        float rc = 1.f / (denp[q] + denp[2 * NBQ + q]);
        float rs = 1.f / (denp[NBQ + q] + denp[3 * NBQ + q]);
        float4 c0 = p4[i];
        float4 s0 = p4[stride + i];
        float4 c1 = p4[2 * stride + i];
        float4 s1 = p4[3 * stride + i];
        float4 r;
        r.x = (c0.x + c1.x) * rc + (s0.x + s1.x) * rs;
        r.y = (c0.y + c1.y) * rc + (s0.y + s1.y) * rs;
        r.z = (c0.z + c1.z) * rc + (s0.z + s1.z) * rs;
        r.w = (c0.w + c1.w) * rc + (s0.w + s1.w) * rs;
        o4[i] = r;
    }
}

extern "C" void kernel_launch(void* const* d_in, const int* in_sizes, int n_in,
                              void* d_out, int out_size, void* d_ws, size_t ws_size,
                              hipStream_t stream)
{
    const float* x      = (const float*)d_in[0];
    const float* ch_mem = (const float*)d_in[1];
    const float* ch_wq  = (const float*)d_in[2];
    const float* ch_wk  = (const float*)d_in[3];
    const float* ch_wv  = (const float*)d_in[4];
    const float* sp_mem = (const float*)d_in[5];
    const float* sp_wq  = (const float*)d_in[6];
    const float* sp_wk  = (const float*)d_in[7];
    const float* sp_wv  = (const float*)d_in[8];
    float* out = (float*)d_out;

    ushort* Qb   = (ushort*)d_ws;                 // [12544][256]
    ushort* QFb  = Qb   + (size_t)NBQ * DM;
    ushort* Kb   = QFb  + (size_t)NBQ * DM;       // [2048][256]
    ushort* KFb  = Kb   + (size_t)MM * DM;
    ushort* Vtb  = KFb  + (size_t)MM * DM;        // [256][2048] transposed
    ushort* VFtb = Vtb  + (size_t)MM * DM;
    float*  km   = (float*)(VFtb + (size_t)MM * DM);
    float*  kv   = km + MM;
    float*  part = kv + MM;                       // [4][12544][256] f32 partial numerators
    float*  denp = part + (size_t)4 * NBQ * DM;   // [4][12544] partial denominators

    const size_t base_b = (2 * (size_t)NBQ * DM + 4 * (size_t)MM * DM) * sizeof(ushort)
                        + 2 * (size_t)MM * sizeof(float);
    const size_t need   = base_b + ((size_t)4 * NBQ * DM + 4 * NBQ) * sizeof(float);
    const bool split = ws_size >= need;

    dim3 blk(256);
    gemm_proj_all<<<dim3(1040), blk, 0, stream>>>(
        x, ch_mem, ch_wq, ch_wk, ch_wv, sp_mem, sp_wq, sp_wk, sp_wv,
        Qb, QFb, Kb, KFb, Vtb, VFtb);
    row_stats_kf<<<dim3(MM / 4), blk, 0, stream>>>(KFb, km, kv);
    if (split) {
        fused_attn_st<2><<<dim3(2 * NBQ / 32), blk, 0, stream>>>(
            Qb, QFb, Kb, KFb, Vtb, VFtb, km, kv, out, part, denp);
        combine_halves<<<dim3(NBQ * DM / 4 / 512), blk, 0, stream>>>(part, denp, out);
    } else {
        fused_attn_st<1><<<dim3(NBQ / 32), blk, 0, stream>>>(
            Qb, QFb, Kb, KFb, Vtb, VFtb, km, kv, out, part, denp);
    }
}